// Round 5
// baseline (607.678 us; speedup 1.0000x reference)
//
#include <hip/hip_runtime.h>

// Problem dims (fixed by setup_inputs): B=4,S=2048 -> M=8192; K=4096; N=4096; bits=4; group=128
#define KD 4096
#define ND 4096
#define GRP 32          // K / group_size = scale groups per output row
#define NT (KD / 64)    // 64 K-tiles of BK=64

typedef unsigned short u16;
typedef float   f32x4  __attribute__((ext_vector_type(4)));
typedef __bf16  bf16x8 __attribute__((ext_vector_type(8)));
typedef unsigned short u16x8 __attribute__((ext_vector_type(8)));
typedef unsigned short u16x4 __attribute__((ext_vector_type(4)));

__device__ __forceinline__ u16 f2bf(float f) {        // RNE float->bf16
  unsigned u = __float_as_uint(f);
  return (u16)((u + 0x7fffu + ((u >> 16) & 1u)) >> 16);
}

__device__ __forceinline__ void async16(const void* g, void* l) {
  // global -> LDS direct copy, 16B per lane, dest = wave-uniform base + lane*16
  __builtin_amdgcn_global_load_lds(
      (const __attribute__((address_space(1))) unsigned int*)g,
      (__attribute__((address_space(3))) unsigned int*)l, 16, 0, 0);
}

// ---------------- prepass: grid-stride, 2048 blocks ----------------
__global__ __launch_bounds__(256) void prep_kernel(
    const int* __restrict__ qw, const float* __restrict__ scale,
    const float* __restrict__ zp, u16* __restrict__ wout,
    const float4* __restrict__ x, u16x4* __restrict__ xb, int nx) {
  const int nth = gridDim.x * 256;
  const int t0 = blockIdx.x * 256 + threadIdx.x;
  for (int idx4 = t0; idx4 < ND * (KD / 32); idx4 += nth) {
    int n = idx4 >> 7;                          // 128 int4 per row
    int p4 = idx4 & 127;
    int g = p4 >> 2;                            // 4 int32 per iter, 16 int32/group
    float s = scale[n * GRP + g];
    float bz = -s * zp[n * GRP + g];            // w = q*s - s*zp
    int4 q4 = ((const int4*)qw)[idx4];
    const unsigned qv[4] = {(unsigned)q4.x, (unsigned)q4.y,
                            (unsigned)q4.z, (unsigned)q4.w};
#pragma unroll
    for (int k = 0; k < 4; ++k) {
      u16x8 hv;
#pragma unroll
      for (int i = 0; i < 8; ++i)
        hv[i] = f2bf(fmaf((float)((qv[k] >> (4 * i)) & 15u), s, bz));
      *(u16x8*)(wout + (size_t)idx4 * 32 + k * 8) = hv;
    }
  }
  for (int i = t0; i < nx; i += nth) {
    float4 v = x[i];
    u16x4 h;
    h[0] = f2bf(v.x); h[1] = f2bf(v.y); h[2] = f2bf(v.z); h[3] = f2bf(v.w);
    xb[i] = h;
  }
}

// ---------------- main GEMM: 256x256 tile, BK=64, 4 waves x 128x128/wave ----
// Round-5 change vs round-4 (272us, MfmaUtil 44.6%): per-tile accounting shows
// MFMA(2470cy) + LDS reads(192KB ~= 2000cy @ ~112B/cy measured LDS ceiling) +
// VALU(860cy) ~= 5330 ~= the 5540cy observed -> fully SERIALIZED, independent of
// barrier structure (R2/R3/R4 all ~1010-1030 TF). Mechanism: 8 waves exit each
// tile barrier together, burst 192 reads; LDS round-robin means every wave's
// last read returns late; all MFMA late together. Lockstep re-forms every tile.
// Fix attacks both terms:
//  (a) per-wave output 128x128 (4 waves, wave grid 2x2) -> LDS-read economics
//      64 FLOP/B vs 42.7 (reads/tile 192KB -> 128KB; + writes 64KB).
//  (b) 1 wave/SIMD: overlap comes from ILP within one instruction stream
//      (MFMA issue ~2cy, pipe 19cy -> wave issues ds_reads between MFMAs;
//      compiler's fine lgkmcnt scheduling does this [m97 asm evidence]).
//      No LDS contention burst, nothing to round-robin.
// Registers: acc 8x8xf32x4 = 256 + b[8] 32 + a[8] 32 + addr ~24 -> ~340 of 512.
// Sync skeleton unchanged from R4 (refcheck-passed): stage(t+1) -> compute(t)
// -> vmcnt(0) + s_barrier. Stage lead = full tile >> 900cy HBM latency.
// LDS swizzle (0-conflict verified): 16B chunk c of row r at slot c^(r&7);
// global_load_lds dest is linear, so lane l pre-fetches source chunk (l&7)^(l>>3).
// C/D: col = lane&15, row = (lane>>4)*4 + reg   [m89/m91-verified]
__global__ __launch_bounds__(256, 1) void gemm256(
    const u16* __restrict__ xb, const u16* __restrict__ wb,
    const float* __restrict__ bias, float* __restrict__ out) {
  __shared__ u16 As[2][256 * 64];
  __shared__ u16 Bs[2][256 * 64];
  const int tid = threadIdx.x;
  const int l = tid & 63, w = tid >> 6;          // 4 waves
  const int wr = w >> 1, wc = w & 1;             // wave grid 2x2
  const int col = l & 15, quad = l >> 4, rsw = col & 7;
  const int lr = l >> 3, csrc = (l & 7) ^ lr;

  // bijective XCD-chunked swizzle (m204); nwg=512 -> exact
  const int id = blockIdx.y * gridDim.x + blockIdx.x;
  const int nwg = gridDim.x * gridDim.y;
  const int q = nwg >> 3, r = nwg & 7;
  const int xcd = id & 7, off = id >> 3;
  const int wgid = (xcd < r ? xcd * (q + 1) : r * (q + 1) + (xcd - r) * q) + off;
  const int nb = gridDim.x;
  const int m0 = (wgid / nb) * 256;
  const int n0 = (wgid % nb) * 256;

  // staging: each wave stages 64 rows of A and 64 rows of B per tile (8 calls each)
  const u16* asrc = xb + (size_t)(m0 + w * 64 + lr) * KD + csrc * 8;
  const u16* bsrc = wb + (size_t)(n0 + w * 64 + lr) * KD + csrc * 8;

#define STAGE(t)                                                           \
  do {                                                                     \
    _Pragma("unroll")                                                      \
    for (int c = 0; c < 8; ++c) {                                          \
      async16(asrc + (size_t)(c * 8) * KD + (t) * 64,                      \
              &As[(t) & 1][(w * 64 + c * 8) * 64]);                        \
      async16(bsrc + (size_t)(c * 8) * KD + (t) * 64,                      \
              &Bs[(t) & 1][(w * 64 + c * 8) * 64]);                        \
    }                                                                      \
  } while (0)
#define BAR()   __builtin_amdgcn_s_barrier()
#define SB0()   __builtin_amdgcn_sched_barrier(0)
#define LDA(Ab, i, kk) \
  (*(const bf16x8*)&(Ab)[(wr * 128 + (i) * 16 + col) * 64 + ((((kk) * 4 + quad) ^ rsw) * 8)])
#define LDB(Bb, j, kk) \
  (*(const bf16x8*)&(Bb)[(wc * 128 + (j) * 16 + col) * 64 + ((((kk) * 4 + quad) ^ rsw) * 8)])
// Whole-tile compute: 2 kk-halves; per half 16 ds_read_b128 + 64 MFMA.
// b/a arrays reused across kk (compiler SSA-renames); straight-line, no barriers.
#define COMPUTE(Ab, Bb)                                                    \
  do {                                                                     \
    _Pragma("unroll")                                                      \
    for (int kk = 0; kk < 2; ++kk) {                                       \
      _Pragma("unroll")                                                    \
      for (int j = 0; j < 8; ++j) b[j] = LDB(Bb, j, kk);                   \
      _Pragma("unroll")                                                    \
      for (int i = 0; i < 8; ++i) a[i] = LDA(Ab, i, kk);                   \
      _Pragma("unroll")                                                    \
      for (int i = 0; i < 8; ++i)                                          \
        _Pragma("unroll")                                                  \
        for (int j = 0; j < 8; ++j)                                        \
          acc[i][j] = __builtin_amdgcn_mfma_f32_16x16x32_bf16(             \
              a[i], b[j], acc[i][j], 0, 0, 0);                             \
    }                                                                      \
  } while (0)
#define DRAIN() do { asm volatile("s_waitcnt vmcnt(0)"); SB0(); BAR(); } while (0)

  f32x4 acc[8][8] = {};
  bf16x8 a[8], b[8];

  // prologue: stage tile 0 into buf0, drain, barrier
  STAGE(0);
  DRAIN();

  for (int tt = 0; tt < NT - 2; tt += 2) {
    STAGE(tt + 1);             // -> buf1 (disjoint from buf0 being read)
    SB0();                     // pin stage-issue before the tile's ds_reads
    COMPUTE(As[0], Bs[0]);
    DRAIN();                   // tile tt+1 landed; buf0 free for rewrite
    STAGE(tt + 2);             // -> buf0
    SB0();
    COMPUTE(As[1], Bs[1]);
    DRAIN();
  }
  // tail: stage last tile, compute NT-2, then NT-1 (no further staging)
  STAGE(NT - 1);               // -> buf1
  SB0();
  COMPUTE(As[0], Bs[0]);
  DRAIN();
  COMPUTE(As[1], Bs[1]);

  // epilogue: add bias, store fp32
#pragma unroll
  for (int j = 0; j < 8; ++j) {
    int n = n0 + wc * 128 + j * 16 + col;
    float bj = bias[n];
#pragma unroll
    for (int i = 0; i < 8; ++i) {
      int mrow = m0 + wr * 128 + i * 16 + quad * 4;
#pragma unroll
      for (int rr = 0; rr < 4; ++rr)
        out[(size_t)(mrow + rr) * ND + n] = acc[i][j][rr] + bj;
    }
  }
#undef STAGE
#undef BAR
#undef SB0
#undef LDA
#undef LDB
#undef COMPUTE
#undef DRAIN
}

// ---------------- fallback GEMM (old 128x128 m97-style kernel, kept for small ws) ----
template <int XF32, int WQ>
__global__ __launch_bounds__(256, 3) void gemm_kernel(
    const u16*   __restrict__ xbp,
    const float* __restrict__ xf,
    const u16*   __restrict__ wbp,
    const int*   __restrict__ qw,
    const float* __restrict__ scale,
    const float* __restrict__ zp,
    const float* __restrict__ bias,
    float* __restrict__ out) {
  __shared__ u16 As[128 * 64];
  __shared__ u16 Bs[128 * 64];
  const int tid = threadIdx.x;
  const int l = tid & 63, w = tid >> 6;
  const int m0 = blockIdx.y * 128, n0 = blockIdx.x * 128;
  const int wm = (w >> 1) * 64, wn = (w & 1) * 64;
  const int col = l & 15, quad = l >> 4;
  const int rsw = col & 7;
  const int lr = l >> 3;
  const int csrc = (l & 7) ^ lr;
  f32x4 acc[4][4] = {};

  for (int k0 = 0; k0 < KD; k0 += 64) {
    __syncthreads();

    if constexpr (XF32) {
#pragma unroll
      for (int it = 0; it < 8; ++it) {
        int fi = it * 256 + tid;
        int row = fi >> 4, cs = fi & 15;
        float4 v = *(const float4*)(xf + (size_t)(m0 + row) * KD + k0 + cs * 4);
        u16x4 h;
        h[0] = f2bf(v.x); h[1] = f2bf(v.y); h[2] = f2bf(v.z); h[3] = f2bf(v.w);
        int slot = (cs >> 1) ^ (row & 7);
        *(u16x4*)(&As[row * 64 + slot * 8 + (cs & 1) * 4]) = h;
      }
    } else {
#pragma unroll
      for (int c = 0; c < 4; ++c) {
        int br = w * 32 + c * 8;
        const u16* g = xbp + (size_t)(m0 + br + lr) * KD + k0 + csrc * 8;
        async16(g, &As[br * 64]);
      }
    }

    if constexpr (WQ) {
#pragma unroll
      for (int it = 0; it < 4; ++it) {
        int qi = it * 256 + tid;
        int row = qi >> 3, p8 = qi & 7;
        int nrow = n0 + row;
        int g = k0 >> 7;
        float s = scale[nrow * GRP + g];
        float bz = -s * zp[nrow * GRP + g];
        unsigned qv = (unsigned)qw[(size_t)nrow * (KD / 8) + (k0 >> 3) + p8];
        u16x8 hv;
#pragma unroll
        for (int i = 0; i < 8; ++i)
          hv[i] = f2bf(fmaf((float)((qv >> (4 * i)) & 15u), s, bz));
        *(u16x8*)(&Bs[row * 64 + ((p8 ^ (row & 7)) * 8)]) = hv;
      }
    } else {
#pragma unroll
      for (int c = 0; c < 4; ++c) {
        int br = w * 32 + c * 8;
        const u16* g = wbp + (size_t)(n0 + br + lr) * KD + k0 + csrc * 8;
        async16(g, &Bs[br * 64]);
      }
    }

    __syncthreads();

#pragma unroll
    for (int kk = 0; kk < 2; ++kk) {
      bf16x8 a[4], b[4];
      const int slot = ((kk * 4 + quad) ^ rsw) * 8;
#pragma unroll
      for (int i = 0; i < 4; ++i)
        a[i] = *(const bf16x8*)&As[(wm + i * 16 + col) * 64 + slot];
#pragma unroll
      for (int j = 0; j < 4; ++j)
        b[j] = *(const bf16x8*)&Bs[(wn + j * 16 + col) * 64 + slot];
#pragma unroll
      for (int i = 0; i < 4; ++i)
#pragma unroll
        for (int j = 0; j < 4; ++j)
          acc[i][j] = __builtin_amdgcn_mfma_f32_16x16x32_bf16(a[i], b[j], acc[i][j], 0, 0, 0);
    }
  }

#pragma unroll
  for (int j = 0; j < 4; ++j) {
    int n = n0 + wn + j * 16 + col;
    float bj = bias[n];
#pragma unroll
    for (int i = 0; i < 4; ++i) {
      int mrow = m0 + wm + i * 16 + quad * 4;
#pragma unroll
      for (int rr = 0; rr < 4; ++rr)
        out[(size_t)(mrow + rr) * ND + n] = acc[i][j][rr] + bj;
    }
  }
}

extern "C" void kernel_launch(void* const* d_in, const int* in_sizes, int n_in,
                              void* d_out, int out_size, void* d_ws, size_t ws_size,
                              hipStream_t stream) {
  const float* x     = (const float*)d_in[0];
  const int*   qw    = (const int*)d_in[1];
  const float* scale = (const float*)d_in[2];
  const float* zp    = (const float*)d_in[3];
  const float* bias  = (const float*)d_in[4];
  float* out = (float*)d_out;

  const int M = in_sizes[0] / KD;  // 8192

  const size_t needW = (size_t)ND * KD * sizeof(u16);  // 32 MB
  const size_t needX = (size_t)M * KD * sizeof(u16);   // 64 MB

  if (ws_size >= needW + needX && (M % 256) == 0) {
    u16* wb = (u16*)d_ws;
    u16* xbuf = wb + (size_t)ND * KD;
    prep_kernel<<<2048, 256, 0, stream>>>(qw, scale, zp, wb,
                                          (const float4*)x, (u16x4*)xbuf,
                                          M * (KD / 4));
    dim3 grid(ND / 256, M / 256);
    gemm256<<<grid, dim3(256), 0, stream>>>(xbuf, wb, bias, out);
  } else if (ws_size >= needW) {
    u16* wb = (u16*)d_ws;
    prep_kernel<<<2048, 256, 0, stream>>>(qw, scale, zp, wb, nullptr, nullptr, 0);
    dim3 grid(ND / 128, M / 128);
    gemm_kernel<1, 0><<<grid, dim3(256), 0, stream>>>(nullptr, x, wb, qw, scale, zp, bias, out);
  } else {
    dim3 grid(ND / 128, M / 128);
    gemm_kernel<1, 1><<<grid, dim3(256), 0, stream>>>(nullptr, x, nullptr, qw, scale, zp, bias, out);
  }
}